// Round 2
// baseline (561.627 us; speedup 1.0000x reference)
//
#include <hip/hip_runtime.h>
#include <hip/hip_bf16.h>

// B=2, DIM=32, CV=HDIM=96, H=W=512, FOLD=8 -> 128 tiles of 64x64, S=4 (P=2), NCLS=16.
// R2: anti-aliasing restructure. All concurrent load streams made contiguous /
// non-power-of-2-strided. k_pool streams 32KB contiguous per wave AND writes an
// f32 re-tiled stash [tile][g=row/4][ch][256px]; pass2/pass3 read the stash
// (1KB channel stride, diverse cache sets / HBM channels) instead of 1MB-strided
// planes. g-cache interleaved [tile][px][4] for coalesced float4 access.
// All math bitwise-identical f32 vs previous version.

// ---- ws layout (float offsets) ----
#define OFF_POOLX   0          // [128][32][4]
#define OFF_POOLS   16384      // [128][31][4]
#define OFF_CENPF0  32256      // [128][96][4]
#define OFF_UDF     81408      // [128][4][32]
#define OFF_USF     97792      // [128][4][31]
#define OFF_GCONST  113664     // [128][4]
#define OFF_NORM0   114176     // [128][4]
#define OFF_NUM1    114688     // [128][96][4]  (zeroed, atomics)
#define OFF_DEN1    163840     // [128][4]      (zeroed, atomics)
#define OFF_CENPF1  164352     // [128][96][4]
#define OFF_NORM1   213504     // [128][4]
#define OFF_OUTNUM  214016     // [128][96][4]  (zeroed, atomics)
#define OFF_OUTDEN  263168     // [128][4]      (zeroed, atomics)
#define OFF_LABELS  263680     // [128][4][16]  (zeroed, atomics)
#define OFF_G       271872     // [128][4096][4] f32 (interleaved: px-major, s-minor)
#define OFF_STASH   16777216   // [128][16][159][256] f32 re-tiled inputs (333 MB)
#define CHSTRIDE    256        // floats per (ch) row in stash
#define GSTRIDE     40704      // 159*256 floats per (tile,g)

// ---- d_out layout (float elements) ----
#define OUT_CF 0        // center_feat [2][256][96]
#define OUT_LB 49152    // labels      [2][16][256]
#define OUT_SP 57344    // spix_map    [2][512][512]

typedef float f32x4 __attribute__((ext_vector_type(4)));
typedef short bf16x8 __attribute__((ext_vector_type(8)));

__device__ __forceinline__ float bf2f(unsigned short u) {
  return __uint_as_float(((unsigned)u) << 16);
}
__device__ __forceinline__ unsigned short f2bf(float f) {
  return (unsigned short)(__float_as_uint(f) >> 16);   // truncate; tolerant paths only
}

// K1 v4: block per (plane 0..317, f1 band 0..7). Wave w owns 16 contiguous rows
// [w*16, w*16+16) -> reads a CONTIGUOUS 32KB stream in 1KB steps (no 4KB stride
// aliasing). Also writes the f32 stash re-tiled per (tile, rowgroup).
__global__ __launch_bounds__(256) void k_pool(const float* __restrict__ x,
    const float* __restrict__ feat, const float* __restrict__ sdf,
    float* __restrict__ ws) {
  int plane = blockIdx.x, f1 = blockIdx.y, tid = threadIdx.x;
  int b = plane / 159, ch = plane % 159;
  const float* src; int c, C, cls;
  if (ch < 32)      { src = x;    C = 32; c = ch;      cls = 0; }
  else if (ch < 63) { src = sdf;  C = 31; c = ch - 32; cls = 1; }
  else              { src = feat; C = 96; c = ch - 63; cls = 2; }
  int wave = tid >> 6, L = tid & 63;
  const float* base = src + ((size_t)(b*C + c)*512 + f1*64 + wave*16)*512 + L*4;
  int tile0 = b*64 + f1*8;
  // stash base pieces (float offsets); f2/g/px vary per load
  int stash0 = OFF_STASH + ch*CHSTRIDE + (L & 15)*4;
  float accE = 0.f, accO = 0.f;    // colHalf 0 (f2=L>>4) / colHalf 1 (f2=4+(L>>4))
  float4 v[16];
  #pragma unroll
  for (int jb = 0; jb < 2; ++jb) {
    #pragma unroll
    for (int j = 0; j < 16; ++j)
      v[j] = *reinterpret_cast<const float4*>(base + (size_t)(jb*16 + j)*256);
    #pragma unroll
    for (int j = 0; j < 16; ++j) {
      int jj = jb*16 + j;
      int row = wave*16 + (jj >> 1);        // tile-row 0..63
      int colHalf = jj & 1;
      int f2 = colHalf*4 + (L >> 4);
      int g = row >> 2;
      int px = (row & 3)*64;
      float4 t = v[j];
      *reinterpret_cast<float4*>(ws + stash0 +
          (size_t)((tile0 + f2)*16 + g)*GSTRIDE + px) = t;
      float s4 = t.x + t.y + t.z + t.w;
      if (colHalf == 0) accE += s4; else accO += s4;
    }
  }
  // 8 lanes share (f2, qx); reduce within group
  accE += __shfl_xor(accE, 1, 64); accE += __shfl_xor(accE, 2, 64); accE += __shfl_xor(accE, 4, 64);
  accO += __shfl_xor(accO, 1, 64); accO += __shfl_xor(accO, 2, 64); accO += __shfl_xor(accO, 4, 64);
  __shared__ float part[4][16];    // [wave][f2*2+qx]
  if ((L & 7) == 0) {
    int qx = (L >> 3) & 1, fE = L >> 4;
    part[wave][fE*2 + qx] = accE;
    part[wave][(4 + fE)*2 + qx] = accO;
  }
  __syncthreads();
  if (tid < 32) {
    int f2 = tid >> 2, qx = (tid >> 1) & 1, qy = tid & 1;
    int idx = f2*2 + qx;
    float val = (part[qy*2][idx] + part[qy*2 + 1][idx]) * (1.f/1024.f);
    int tile = tile0 + f2, s = qy*2 + qx;
    float* dst;
    if (cls == 0)      dst = ws + OFF_POOLX  + (tile*32 + c)*4;
    else if (cls == 1) dst = ws + OFF_POOLS  + (tile*31 + c)*4;
    else               dst = ws + OFF_CENPF0 + (tile*96 + c)*4;
    dst[s] = val;
  }
}

// K2: per tile: cen_df/cen_sf from pooled x/sdf; u_df, u_sf, gconst, norm0.
__global__ __launch_bounds__(384) void k_centers(const float* __restrict__ Wf,
    const float* __restrict__ bfv, const float* __restrict__ Wsdf,
    const float* __restrict__ bsdf, float* __restrict__ ws) {
  int tile = blockIdx.x, tid = threadIdx.x;
  __shared__ float px[128];
  __shared__ float ps[124];
  __shared__ float cdf[384];
  __shared__ float csf[384];
  __shared__ float redg[4], redn[4];
  if (tid < 128) px[tid] = ws[OFF_POOLX + tile*128 + tid];
  if (tid < 124) ps[tid] = ws[OFF_POOLS + tile*124 + tid];
  if (tid < 4) { redg[tid] = 0.f; redn[tid] = 0.f; }
  __syncthreads();
  int c = tid % 96, s = tid / 96;
  float bc = bfv[c];
  float a = bc;
  for (int k = 0; k < 32; ++k) a += Wf[c*32 + k] * px[k*4 + s];
  cdf[c*4 + s] = a;
  float bs = bsdf[c];
  float a2 = bs;
  for (int k = 0; k < 31; ++k) a2 += Wsdf[c*31 + k] * ps[k*4 + s];
  csf[c*4 + s] = a2;
  atomicAdd(&redg[s], 2.f*(bc*a + bs*a2) - (a*a + a2*a2));
  float cp = ws[OFF_CENPF0 + tile*384 + c*4 + s];
  atomicAdd(&redn[s], cp*cp);
  __syncthreads();
  if (tid < 128) {
    int s2 = tid >> 5, k = tid & 31;
    float u = 0.f;
    for (int c2 = 0; c2 < 96; ++c2) u += Wf[c2*32 + k] * cdf[c2*4 + s2];
    ws[OFF_UDF + tile*128 + tid] = u;
  } else if (tid < 252) {
    int t2 = tid - 128, s2 = t2 / 31, k = t2 % 31;
    float u = 0.f;
    for (int c2 = 0; c2 < 96; ++c2) u += Wsdf[c2*31 + k] * csf[c2*4 + s2];
    ws[OFF_USF + tile*124 + t2] = u;
  }
  if (tid < 4) { ws[OFF_GCONST + tile*4 + tid] = redg[tid]; ws[OFF_NORM0 + tile*4 + tid] = redn[tid]; }
}

// K3: SSN iter0, reading the re-tiled stash (1KB channel stride - no aliasing).
__global__ __launch_bounds__(256) void k_pass2(const float* __restrict__ x,
    const float* __restrict__ feat, const float* __restrict__ sdf,
    float* __restrict__ ws) {
  int wg = blockIdx.x, tile = wg >> 2, seg = wg & 3, tid = threadIdx.x;
  __shared__ float s_cpf0[384];
  __shared__ float s_udf[128];
  __shared__ float s_usf[124];
  __shared__ float s_gc[4], s_n0[4];
  __shared__ __align__(16) unsigned short s_pfT[96][264];  // [c][px] bf16
  __shared__ __align__(16) unsigned short s_aT[16][264];   // [n][px] bf16; rows 4..15 zero
  for (int i = tid; i < 384; i += 256) s_cpf0[i] = ws[OFF_CENPF0 + tile*384 + i];
  if (tid < 128) s_udf[tid] = ws[OFF_UDF + tile*128 + tid];
  if (tid < 124) s_usf[tid] = ws[OFF_USF + tile*124 + tid];
  if (tid < 4) { s_gc[tid] = ws[OFF_GCONST + tile*4 + tid]; s_n0[tid] = ws[OFF_NORM0 + tile*4 + tid]; }
  for (int i = tid; i < 16*264; i += 256) (&s_aT[0][0])[i] = 0;
  __syncthreads();
  int lane = tid & 63, wave = tid >> 6;
  int mrow = lane & 15, quad = lane >> 4;
  f32x4 zero4 = {0.f, 0.f, 0.f, 0.f};
  f32x4 accC[6] = {zero4, zero4, zero4, zero4, zero4, zero4};
  float dden[4] = {0.f, 0.f, 0.f, 0.f};
  for (int chunk = 0; chunk < 4; ++chunk) {
    int g = seg*4 + chunk;
    int p = seg*1024 + chunk*256 + tid;
    const float* SB = ws + OFF_STASH + (size_t)(tile*16 + g)*GSTRIDE + tid;
    float vv[16];
    float d0=0.f,d1=0.f,d2=0.f,d3=0.f;
    #pragma unroll
    for (int kb = 0; kb < 32; kb += 16) {
      #pragma unroll
      for (int j = 0; j < 16; ++j) vv[j] = SB[(size_t)(kb + j)*CHSTRIDE];
      #pragma unroll
      for (int j = 0; j < 16; ++j) {
        float v = vv[j]; int k = kb + j;
        d0 += v*s_udf[k]; d1 += v*s_udf[32+k]; d2 += v*s_udf[64+k]; d3 += v*s_udf[96+k];
      }
    }
    {
      #pragma unroll
      for (int j = 0; j < 16; ++j) vv[j] = SB[(size_t)(32 + j)*CHSTRIDE];
      #pragma unroll
      for (int j = 0; j < 16; ++j) {
        float v = vv[j];
        d0 += v*s_usf[j]; d1 += v*s_usf[31+j]; d2 += v*s_usf[62+j]; d3 += v*s_usf[93+j];
      }
      #pragma unroll
      for (int j = 0; j < 15; ++j) vv[j] = SB[(size_t)(48 + j)*CHSTRIDE];
      #pragma unroll
      for (int j = 0; j < 15; ++j) {
        float v = vv[j]; int k = 16 + j;
        d0 += v*s_usf[k]; d1 += v*s_usf[31+k]; d2 += v*s_usf[62+k]; d3 += v*s_usf[93+k];
      }
    }
    float g0 = 2.f*d0 + s_gc[0], g1 = 2.f*d1 + s_gc[1];
    float g2 = 2.f*d2 + s_gc[2], g3 = 2.f*d3 + s_gc[3];
    {
      f32x4 gv = {g0, g1, g2, g3};
      *reinterpret_cast<f32x4*>(ws + OFF_G + ((size_t)tile << 14) + (size_t)p*4) = gv;
    }
    float p0=0.f,p1=0.f,p2=0.f,p3=0.f;
    #pragma unroll
    for (int cb = 0; cb < 96; cb += 16) {
      #pragma unroll
      for (int j = 0; j < 16; ++j) vv[j] = SB[(size_t)(63 + cb + j)*CHSTRIDE];
      #pragma unroll
      for (int j = 0; j < 16; ++j) {
        float v = vv[j]; int cc = cb + j;
        s_pfT[cc][tid] = f2bf(v);
        p0 += v*s_cpf0[cc*4+0]; p1 += v*s_cpf0[cc*4+1]; p2 += v*s_cpf0[cc*4+2]; p3 += v*s_cpf0[cc*4+3];
      }
    }
    float sc0 = g0 + 2.f*p0 - s_n0[0];
    float sc1 = g1 + 2.f*p1 - s_n0[1];
    float sc2 = g2 + 2.f*p2 - s_n0[2];
    float sc3 = g3 + 2.f*p3 - s_n0[3];
    float m = fmaxf(fmaxf(sc0, sc1), fmaxf(sc2, sc3));
    float e0 = expf(sc0 - m), e1 = expf(sc1 - m), e2 = expf(sc2 - m), e3 = expf(sc3 - m);
    float inv = 1.f / (e0 + e1 + e2 + e3);
    float a0 = e0*inv, a1 = e1*inv, a2 = e2*inv, a3 = e3*inv;
    s_aT[0][tid] = f2bf(a0); s_aT[1][tid] = f2bf(a1);
    s_aT[2][tid] = f2bf(a2); s_aT[3][tid] = f2bf(a3);
    dden[0] += a0; dden[1] += a1; dden[2] += a2; dden[3] += a3;
    __syncthreads();
    // MFMA: wave w handles K-steps 2w, 2w+1 (32 px each)
    #pragma unroll
    for (int kk = 0; kk < 2; ++kk) {
      int k0 = (wave*2 + kk)*32 + quad*8;
      bf16x8 bfrag = *reinterpret_cast<const bf16x8*>(&s_aT[mrow][k0]);
      #pragma unroll
      for (int mt = 0; mt < 6; ++mt) {
        bf16x8 afrag = *reinterpret_cast<const bf16x8*>(&s_pfT[mt*16 + mrow][k0]);
        accC[mt] = __builtin_amdgcn_mfma_f32_16x16x32_bf16(afrag, bfrag, accC[mt], 0, 0, 0);
      }
    }
    __syncthreads();
  }
  if (mrow < 4) {     // C/D: col=lane&15 (=s), row=quad*4+reg (=c within tile)
    #pragma unroll
    for (int mt = 0; mt < 6; ++mt)
      #pragma unroll
      for (int r = 0; r < 4; ++r) {
        int c = mt*16 + quad*4 + r;
        atomicAdd(&ws[OFF_NUM1 + (tile*96 + c)*4 + mrow], accC[mt][r]);
      }
  }
  for (int m2 = 1; m2 < 64; m2 <<= 1) {
    dden[0] += __shfl_xor(dden[0], m2, 64); dden[1] += __shfl_xor(dden[1], m2, 64);
    dden[2] += __shfl_xor(dden[2], m2, 64); dden[3] += __shfl_xor(dden[3], m2, 64);
  }
  if (lane == 0) {
    atomicAdd(&ws[OFF_DEN1 + tile*4 + 0], dden[0]);
    atomicAdd(&ws[OFF_DEN1 + tile*4 + 1], dden[1]);
    atomicAdd(&ws[OFF_DEN1 + tile*4 + 2], dden[2]);
    atomicAdd(&ws[OFF_DEN1 + tile*4 + 3], dden[3]);
  }
}

// K4: cen_pf1 = num/(den+1e-16); norm1[s] = |cen_pf1[:,s]|^2
__global__ __launch_bounds__(384) void k_fin1(float* __restrict__ ws) {
  int tile = blockIdx.x, tid = threadIdx.x;
  __shared__ float red[4];
  if (tid < 4) red[tid] = 0.f;
  __syncthreads();
  int c = tid % 96, s = tid / 96;
  float den = ws[OFF_DEN1 + tile*4 + s];
  float v = ws[OFF_NUM1 + (tile*96 + c)*4 + s] / (den + 1e-16f);
  ws[OFF_CENPF1 + (tile*96 + c)*4 + s] = v;
  atomicAdd(&red[s], v*v);
  __syncthreads();
  if (tid < 4) ws[OFF_NORM1 + tile*4 + tid] = red[tid];
}

// K5: SSN iter1: final scores from cached g (coalesced float4); feat from stash.
__global__ __launch_bounds__(256) void k_pass3(const float* __restrict__ feat,
    const int* __restrict__ gt, float* __restrict__ ws, float* __restrict__ out) {
  int wg = blockIdx.x, tile = wg >> 2, seg = wg & 3, tid = threadIdx.x;
  int b = tile >> 6, tl = tile & 63, f1 = tl >> 3, f2 = tl & 7;
  __shared__ float s_cpf1[384];
  __shared__ float s_n1[4];
  __shared__ __align__(16) unsigned short s_pfT[96][264];
  __shared__ __align__(16) unsigned short s_aT[16][264];
  __shared__ float s_hist[64];
  for (int i = tid; i < 384; i += 256) s_cpf1[i] = ws[OFF_CENPF1 + tile*384 + i];
  if (tid < 4) s_n1[tid] = ws[OFF_NORM1 + tile*4 + tid];
  if (tid < 64) s_hist[tid] = 0.f;
  for (int i = tid; i < 16*264; i += 256) (&s_aT[0][0])[i] = 0;
  __syncthreads();
  int lane = tid & 63, wave = tid >> 6;
  int mrow = lane & 15, quad = lane >> 4;
  f32x4 zero4 = {0.f, 0.f, 0.f, 0.f};
  f32x4 accC[6] = {zero4, zero4, zero4, zero4, zero4, zero4};
  float oden[4] = {0.f, 0.f, 0.f, 0.f};
  for (int chunk = 0; chunk < 4; ++chunk) {
    int g = seg*4 + chunk;
    int p = seg*1024 + chunk*256 + tid;
    int y = p >> 6, xx = p & 63;
    int go = (f1*64 + y)*512 + f2*64 + xx;
    f32x4 gv = *reinterpret_cast<const f32x4*>(ws + OFF_G + ((size_t)tile << 14) + (size_t)p*4);
    const float* SB = ws + OFF_STASH + (size_t)(tile*16 + g)*GSTRIDE + tid;
    float vv[16];
    float p0=0.f,p1=0.f,p2=0.f,p3=0.f;
    #pragma unroll
    for (int cb = 0; cb < 96; cb += 16) {
      #pragma unroll
      for (int j = 0; j < 16; ++j) vv[j] = SB[(size_t)(63 + cb + j)*CHSTRIDE];
      #pragma unroll
      for (int j = 0; j < 16; ++j) {
        float v = vv[j]; int cc = cb + j;
        s_pfT[cc][tid] = f2bf(v);
        p0 += v*s_cpf1[cc*4+0]; p1 += v*s_cpf1[cc*4+1]; p2 += v*s_cpf1[cc*4+2]; p3 += v*s_cpf1[cc*4+3];
      }
    }
    float sc0 = gv[0] + 2.f*p0 - s_n1[0];
    float sc1 = gv[1] + 2.f*p1 - s_n1[1];
    float sc2 = gv[2] + 2.f*p2 - s_n1[2];
    float sc3 = gv[3] + 2.f*p3 - s_n1[3];
    int ss = 0; float best = sc0;
    if (sc1 > best) { best = sc1; ss = 1; }
    if (sc2 > best) { best = sc2; ss = 2; }
    if (sc3 > best) { best = sc3; ss = 3; }
    float se = expf(sc0-best) + expf(sc1-best) + expf(sc2-best) + expf(sc3-best);
    float sim = 1.f / se;
    unsigned short sb = f2bf(sim);
    s_aT[0][tid] = (ss == 0) ? sb : (unsigned short)0;
    s_aT[1][tid] = (ss == 1) ? sb : (unsigned short)0;
    s_aT[2][tid] = (ss == 2) ? sb : (unsigned short)0;
    s_aT[3][tid] = (ss == 3) ? sb : (unsigned short)0;
    oden[ss] += sim;
    int gv2 = gt[b*262144 + go];
    atomicAdd(&s_hist[ss*16 + gv2], 1.f);
    out[OUT_SP + b*262144 + go] = (float)(tl*4 + ss);
    __syncthreads();
    #pragma unroll
    for (int kk = 0; kk < 2; ++kk) {
      int k0 = (wave*2 + kk)*32 + quad*8;
      bf16x8 bfrag = *reinterpret_cast<const bf16x8*>(&s_aT[mrow][k0]);
      #pragma unroll
      for (int mt = 0; mt < 6; ++mt) {
        bf16x8 afrag = *reinterpret_cast<const bf16x8*>(&s_pfT[mt*16 + mrow][k0]);
        accC[mt] = __builtin_amdgcn_mfma_f32_16x16x32_bf16(afrag, bfrag, accC[mt], 0, 0, 0);
      }
    }
    __syncthreads();
  }
  if (mrow < 4) {
    #pragma unroll
    for (int mt = 0; mt < 6; ++mt)
      #pragma unroll
      for (int r = 0; r < 4; ++r) {
        int c = mt*16 + quad*4 + r;
        atomicAdd(&ws[OFF_OUTNUM + (tile*96 + c)*4 + mrow], accC[mt][r]);
      }
  }
  for (int m2 = 1; m2 < 64; m2 <<= 1) {
    oden[0] += __shfl_xor(oden[0], m2, 64); oden[1] += __shfl_xor(oden[1], m2, 64);
    oden[2] += __shfl_xor(oden[2], m2, 64); oden[3] += __shfl_xor(oden[3], m2, 64);
  }
  if (lane == 0) {
    atomicAdd(&ws[OFF_OUTDEN + tile*4 + 0], oden[0]);
    atomicAdd(&ws[OFF_OUTDEN + tile*4 + 1], oden[1]);
    atomicAdd(&ws[OFF_OUTDEN + tile*4 + 2], oden[2]);
    atomicAdd(&ws[OFF_OUTDEN + tile*4 + 3], oden[3]);
  }
  if (tid < 64) atomicAdd(&ws[OFF_LABELS + tile*64 + tid], s_hist[tid]);
}

// K6: epilogue -> center_feat and labels
__global__ __launch_bounds__(384) void k_out(const float* __restrict__ ws,
                                             float* __restrict__ out) {
  int tile = blockIdx.x, tid = threadIdx.x;
  int b = tile >> 6, tl = tile & 63;
  int c = tid % 96, s = tid / 96;
  float od = ws[OFF_OUTDEN + tile*4 + s];
  float v = (ws[OFF_OUTNUM + (tile*96 + c)*4 + s] + ws[OFF_CENPF0 + (tile*96 + c)*4 + s]) / (od + 1.f);
  out[OUT_CF + (size_t)(b*256 + tl*4 + s)*96 + c] = v;
  if (tid < 64) {
    int s2 = tid >> 4, cls = tid & 15;
    float cnt = ws[OFF_LABELS + tile*64 + tid];
    out[OUT_LB + (b*16 + cls)*256 + tl*4 + s2] = cnt;
  }
}

extern "C" void kernel_launch(void* const* d_in, const int* in_sizes, int n_in,
                              void* d_out, int out_size, void* d_ws, size_t ws_size,
                              hipStream_t stream) {
  const float* x    = (const float*)d_in[0];
  const float* feat = (const float*)d_in[1];
  const float* sdf  = (const float*)d_in[2];
  const float* Wf   = (const float*)d_in[3];
  const float* bfv  = (const float*)d_in[4];
  const float* Wsdf = (const float*)d_in[5];
  const float* bsdf = (const float*)d_in[6];
  const int* gt = (const int*)d_in[7];
  float* ws = (float*)d_ws;
  float* out = (float*)d_out;

  hipMemsetAsync(ws + OFF_NUM1, 0,
                 (size_t)(OFF_LABELS + 128*64 - OFF_NUM1) * sizeof(float), stream);

  k_pool   <<<dim3(318, 8), 256, 0, stream>>>(x, feat, sdf, ws);
  k_centers<<<128, 384, 0, stream>>>(Wf, bfv, Wsdf, bsdf, ws);
  k_pass2  <<<512, 256, 0, stream>>>(x, feat, sdf, ws);
  k_fin1   <<<128, 384, 0, stream>>>(ws);
  k_pass3  <<<512, 256, 0, stream>>>(feat, gt, ws, out);
  k_out    <<<128, 384, 0, stream>>>(ws, out);
}

// Round 3
// 491.809 us; speedup vs baseline: 1.1420x; 1.1420x over previous
//
#include <hip/hip_runtime.h>
#include <hip/hip_bf16.h>

// B=2, DIM=32, CV=HDIM=96, H=W=512, FOLD=8 -> 128 tiles of 64x64, S=4 (P=2), NCLS=16.
// R3: stash reverted (read ceiling ~2.8-3 TB/s is pattern-independent; round trip
// costs more than it saves). pass2/pass3 rebuilt around float4 global loads
// (1KB/wave-instr like k_pool) with per-wave channel-subset partials combined in
// LDS (deterministic). fin1 fused into pass3; memset fused into k_pool.

// ---- ws layout (float offsets) ----
#define OFF_POOLX   0          // [128][32][4]
#define OFF_POOLS   16384      // [128][31][4]
#define OFF_CENPF0  32256      // [128][96][4]
#define OFF_UDF     81408      // [128][4][32]
#define OFF_USF     97792      // [128][4][31]
#define OFF_GCONST  113664     // [128][4]
#define OFF_NORM0   114176     // [128][4]
#define OFF_NUM1    114688     // [128][96][4]  (zeroed, atomics)
#define OFF_DEN1    163840     // [128][4]      (zeroed, atomics)
#define OFF_CENPF1  164352     // (unused)
#define OFF_NORM1   213504     // (unused)
#define OFF_OUTNUM  214016     // [128][96][4]  (zeroed, atomics)
#define OFF_OUTDEN  263168     // [128][4]      (zeroed, atomics)
#define OFF_LABELS  263680     // [128][4][16]  (zeroed, atomics)
#define OFF_G       271872     // [128][4096][4] f32 interleaved (px-major, s-minor)
#define ZERO_BASE   OFF_NUM1
#define ZERO_LEN    157184     // floats: NUM1..LABELS end (incl unused CENPF1/NORM1)

// ---- d_out layout (float elements) ----
#define OUT_CF 0        // center_feat [2][256][96]
#define OUT_LB 49152    // labels      [2][16][256]
#define OUT_SP 57344    // spix_map    [2][512][512]

typedef float f32x4 __attribute__((ext_vector_type(4)));
typedef short bf16x8 __attribute__((ext_vector_type(8)));
typedef unsigned short u16x4 __attribute__((ext_vector_type(4)));

__device__ __forceinline__ float bf2f(unsigned short u) {
  return __uint_as_float(((unsigned)u) << 16);
}
__device__ __forceinline__ unsigned short f2bf(float f) {
  return (unsigned short)(__float_as_uint(f) >> 16);   // truncate; tolerant paths only
}

// K1: block per (plane 0..317, f1 band 0..7): reads 64 rows x 512 cols (128 KB),
// writes 8 tiles x 4 quadrant means. Known-good ~118us reader (R1 v3).
// Also zero-inits the atomic ws regions (replaces hipMemsetAsync dispatch).
__global__ __launch_bounds__(256) void k_pool(const float* __restrict__ x,
    const float* __restrict__ feat, const float* __restrict__ sdf,
    float* __restrict__ ws) {
  int plane = blockIdx.x, f1 = blockIdx.y, tid = threadIdx.x;
  // inline zero of atomic regions (2544 blocks x 64 floats covers 157184)
  {
    int lb = blockIdx.y * gridDim.x + blockIdx.x;
    if (tid < 64) {
      int zi = lb * 64 + tid;
      if (zi < ZERO_LEN) ws[ZERO_BASE + zi] = 0.f;
    }
  }
  int b = plane / 159, ch = plane % 159;
  const float* src; int c, C, cls;
  if (ch < 32)      { src = x;    C = 32; c = ch;      cls = 0; }
  else if (ch < 63) { src = sdf;  C = 31; c = ch - 32; cls = 1; }
  else              { src = feat; C = 96; c = ch - 63; cls = 2; }
  const float* base = src + ((size_t)(b*C + c)*512 + f1*64)*512;
  int half = tid >> 7, col4 = tid & 127;
  const float* p0 = base + (size_t)half*512 + (size_t)col4*4;  // rows y=2i+half
  f32x4 v[16];
  float acc0 = 0.f, acc1 = 0.f;    // qy=0 / qy=1
  #pragma unroll
  for (int i = 0; i < 16; ++i)
    v[i] = *reinterpret_cast<const f32x4*>(p0 + (size_t)i*1024);
  #pragma unroll
  for (int i = 0; i < 16; ++i) { f32x4 t = v[i]; acc0 += t[0] + t[1] + t[2] + t[3]; }
  #pragma unroll
  for (int i = 0; i < 16; ++i)
    v[i] = *reinterpret_cast<const f32x4*>(p0 + (size_t)(16 + i)*1024);
  #pragma unroll
  for (int i = 0; i < 16; ++i) { f32x4 t = v[i]; acc1 += t[0] + t[1] + t[2] + t[3]; }
  // 8 consecutive lanes share (f2,qx)
  acc0 += __shfl_xor(acc0, 1, 64); acc0 += __shfl_xor(acc0, 2, 64); acc0 += __shfl_xor(acc0, 4, 64);
  acc1 += __shfl_xor(acc1, 1, 64); acc1 += __shfl_xor(acc1, 2, 64); acc1 += __shfl_xor(acc1, 4, 64);
  __shared__ float part[32][2];    // [(f2*2+qx)*2+qy][half]
  int lane = tid & 63;
  if ((lane & 7) == 0) {
    int f2 = col4 >> 4, qx = (col4 >> 3) & 1;
    part[(f2*2 + qx)*2 + 0][half] = acc0;
    part[(f2*2 + qx)*2 + 1][half] = acc1;
  }
  __syncthreads();
  if (tid < 32) {
    float v2 = (part[tid][0] + part[tid][1]) * (1.f/1024.f);
    int f2 = tid >> 2, qx = (tid >> 1) & 1, qy = tid & 1;
    int tile = b*64 + f1*8 + f2, s = qy*2 + qx;
    float* dst;
    if (cls == 0)      dst = ws + OFF_POOLX  + (tile*32 + c)*4;
    else if (cls == 1) dst = ws + OFF_POOLS  + (tile*31 + c)*4;
    else               dst = ws + OFF_CENPF0 + (tile*96 + c)*4;
    dst[s] = v2;
  }
}

// K2: per tile: cen_df/cen_sf from pooled x/sdf; u_df, u_sf, gconst, norm0.
__global__ __launch_bounds__(384) void k_centers(const float* __restrict__ Wf,
    const float* __restrict__ bfv, const float* __restrict__ Wsdf,
    const float* __restrict__ bsdf, float* __restrict__ ws) {
  int tile = blockIdx.x, tid = threadIdx.x;
  __shared__ float px[128];
  __shared__ float ps[124];
  __shared__ float cdf[384];
  __shared__ float csf[384];
  __shared__ float redg[4], redn[4];
  if (tid < 128) px[tid] = ws[OFF_POOLX + tile*128 + tid];
  if (tid < 124) ps[tid] = ws[OFF_POOLS + tile*124 + tid];
  if (tid < 4) { redg[tid] = 0.f; redn[tid] = 0.f; }
  __syncthreads();
  int c = tid % 96, s = tid / 96;
  float bc = bfv[c];
  float a = bc;
  for (int k = 0; k < 32; ++k) a += Wf[c*32 + k] * px[k*4 + s];
  cdf[c*4 + s] = a;
  float bs = bsdf[c];
  float a2 = bs;
  for (int k = 0; k < 31; ++k) a2 += Wsdf[c*31 + k] * ps[k*4 + s];
  csf[c*4 + s] = a2;
  atomicAdd(&redg[s], 2.f*(bc*a + bs*a2) - (a*a + a2*a2));
  float cp = ws[OFF_CENPF0 + tile*384 + c*4 + s];
  atomicAdd(&redn[s], cp*cp);
  __syncthreads();
  if (tid < 128) {
    int s2 = tid >> 5, k = tid & 31;
    float u = 0.f;
    for (int c2 = 0; c2 < 96; ++c2) u += Wf[c2*32 + k] * cdf[c2*4 + s2];
    ws[OFF_UDF + tile*128 + tid] = u;
  } else if (tid < 252) {
    int t2 = tid - 128, s2 = t2 / 31, k = t2 % 31;
    float u = 0.f;
    for (int c2 = 0; c2 < 96; ++c2) u += Wsdf[c2*31 + k] * csf[c2*4 + s2];
    ws[OFF_USF + tile*124 + t2] = u;
  }
  if (tid < 4) { ws[OFF_GCONST + tile*4 + tid] = redg[tid]; ws[OFF_NORM0 + tile*4 + tid] = redn[tid]; }
}

// K3: SSN iter0. 4 WGs/tile x 1024 px, 4 chunks of 256 px.
// Wide-load redesign: lane L owns px quad [4L..4L+3] of the chunk; wave w loads
// channel subset {w, w+4, ...} as float4 (1KB/wave-instr). Per-wave partial
// score sums combined deterministically via LDS (waves 2,3 store; 0,1 add; pairs
// summed in score phase). pf staged to LDS bf16 for MFMA as before.
__global__ __launch_bounds__(256) void k_pass2(const float* __restrict__ x,
    const float* __restrict__ feat, const float* __restrict__ sdf,
    float* __restrict__ ws) {
  int wg = blockIdx.x, tile = wg >> 2, seg = wg & 3, tid = threadIdx.x;
  int b = tile >> 6, tl = tile & 63, f1 = tl >> 3, f2 = tl & 7;
  __shared__ float s_cpf0[384];
  __shared__ float s_udf[128];
  __shared__ float s_usf[124];
  __shared__ float s_gc[4], s_n0[4];
  __shared__ __align__(16) unsigned short s_pfT[96][264];  // [c][px] bf16
  __shared__ __align__(16) unsigned short s_aT[16][264];   // [n][px] bf16; rows 4..15 zero
  __shared__ __align__(16) float s_part[2][8][260];        // [pair][d0-3,p0-3][px]
  for (int i = tid; i < 384; i += 256) s_cpf0[i] = ws[OFF_CENPF0 + tile*384 + i];
  if (tid < 128) s_udf[tid] = ws[OFF_UDF + tile*128 + tid];
  if (tid < 124) s_usf[tid] = ws[OFF_USF + tile*124 + tid];
  if (tid < 4) { s_gc[tid] = ws[OFF_GCONST + tile*4 + tid]; s_n0[tid] = ws[OFF_NORM0 + tile*4 + tid]; }
  for (int i = tid; i < 16*264; i += 256) (&s_aT[0][0])[i] = 0;
  __syncthreads();
  int lane = tid & 63, wave = tid >> 6;
  int mrow = lane & 15, quad = lane >> 4;
  int q4 = lane * 4;                       // px quad base within chunk
  f32x4 zero4 = {0.f, 0.f, 0.f, 0.f};
  f32x4 accC[6] = {zero4, zero4, zero4, zero4, zero4, zero4};
  float dden[4] = {0.f, 0.f, 0.f, 0.f};
  for (int chunk = 0; chunk < 4; ++chunk) {
    int pq = seg*1024 + chunk*256 + q4;
    int goq = (f1*64 + (pq >> 6))*512 + f2*64 + (pq & 63);
    const float* xq = x   + (size_t)(b*32)*262144 + goq;
    const float* sq = sdf + (size_t)(b*31)*262144 + goq;
    const float* fq = feat+ (size_t)(b*96)*262144 + goq;
    f32x4 dpd[4] = {zero4, zero4, zero4, zero4};
    f32x4 dpp[4] = {zero4, zero4, zero4, zero4};
    f32x4 vv[8];
    // x: channels wave+4i
    #pragma unroll
    for (int i = 0; i < 8; ++i)
      vv[i] = *reinterpret_cast<const f32x4*>(xq + (size_t)(wave + 4*i)*262144);
    #pragma unroll
    for (int i = 0; i < 8; ++i) {
      int ch = wave + 4*i;
      #pragma unroll
      for (int s = 0; s < 4; ++s) dpd[s] += vv[i] * s_udf[s*32 + ch];
    }
    // sdf: channels wave+4i (<31)
    #pragma unroll
    for (int i = 0; i < 8; ++i)
      if (wave + 4*i < 31)
        vv[i] = *reinterpret_cast<const f32x4*>(sq + (size_t)(wave + 4*i)*262144);
    #pragma unroll
    for (int i = 0; i < 8; ++i) {
      int ch = wave + 4*i;
      if (ch < 31) {
        #pragma unroll
        for (int s = 0; s < 4; ++s) dpd[s] += vv[i] * s_usf[s*31 + ch];
      }
    }
    // feat: channels wave+4i, i<24 (3 rounds of 8)
    #pragma unroll
    for (int r = 0; r < 3; ++r) {
      #pragma unroll
      for (int i = 0; i < 8; ++i)
        vv[i] = *reinterpret_cast<const f32x4*>(fq + (size_t)(wave + 4*(r*8 + i))*262144);
      #pragma unroll
      for (int i = 0; i < 8; ++i) {
        int ch = wave + 4*(r*8 + i);
        u16x4 uu = { f2bf(vv[i][0]), f2bf(vv[i][1]), f2bf(vv[i][2]), f2bf(vv[i][3]) };
        *reinterpret_cast<u16x4*>(&s_pfT[ch][q4]) = uu;
        #pragma unroll
        for (int s = 0; s < 4; ++s) dpp[s] += vv[i] * s_cpf0[ch*4 + s];
      }
    }
    // combine partials: waves 2,3 store; waves 0,1 add
    if (wave >= 2) {
      #pragma unroll
      for (int s = 0; s < 4; ++s) {
        *reinterpret_cast<f32x4*>(&s_part[wave-2][s][q4]) = dpd[s];
        *reinterpret_cast<f32x4*>(&s_part[wave-2][4+s][q4]) = dpp[s];
      }
    }
    __syncthreads();
    if (wave < 2) {
      #pragma unroll
      for (int s = 0; s < 4; ++s) {
        f32x4 t = *reinterpret_cast<f32x4*>(&s_part[wave][s][q4]);
        t += dpd[s];
        *reinterpret_cast<f32x4*>(&s_part[wave][s][q4]) = t;
        f32x4 t2 = *reinterpret_cast<f32x4*>(&s_part[wave][4+s][q4]);
        t2 += dpp[s];
        *reinterpret_cast<f32x4*>(&s_part[wave][4+s][q4]) = t2;
      }
    }
    __syncthreads();
    // score phase: px = tid
    float d0 = s_part[0][0][tid] + s_part[1][0][tid];
    float d1 = s_part[0][1][tid] + s_part[1][1][tid];
    float d2 = s_part[0][2][tid] + s_part[1][2][tid];
    float d3 = s_part[0][3][tid] + s_part[1][3][tid];
    float p0 = s_part[0][4][tid] + s_part[1][4][tid];
    float p1 = s_part[0][5][tid] + s_part[1][5][tid];
    float p2 = s_part[0][6][tid] + s_part[1][6][tid];
    float p3 = s_part[0][7][tid] + s_part[1][7][tid];
    float g0 = 2.f*d0 + s_gc[0], g1 = 2.f*d1 + s_gc[1];
    float g2 = 2.f*d2 + s_gc[2], g3 = 2.f*d3 + s_gc[3];
    int p = seg*1024 + chunk*256 + tid;
    {
      f32x4 gv = {g0, g1, g2, g3};
      *reinterpret_cast<f32x4*>(ws + OFF_G + ((size_t)tile << 14) + (size_t)p*4) = gv;
    }
    float sc0 = g0 + 2.f*p0 - s_n0[0];
    float sc1 = g1 + 2.f*p1 - s_n0[1];
    float sc2 = g2 + 2.f*p2 - s_n0[2];
    float sc3 = g3 + 2.f*p3 - s_n0[3];
    float m = fmaxf(fmaxf(sc0, sc1), fmaxf(sc2, sc3));
    float e0 = expf(sc0 - m), e1 = expf(sc1 - m), e2 = expf(sc2 - m), e3 = expf(sc3 - m);
    float inv = 1.f / (e0 + e1 + e2 + e3);
    float a0 = e0*inv, a1 = e1*inv, a2 = e2*inv, a3 = e3*inv;
    s_aT[0][tid] = f2bf(a0); s_aT[1][tid] = f2bf(a1);
    s_aT[2][tid] = f2bf(a2); s_aT[3][tid] = f2bf(a3);
    dden[0] += a0; dden[1] += a1; dden[2] += a2; dden[3] += a3;
    __syncthreads();
    // MFMA: wave w handles K-steps 2w, 2w+1 (32 px each)
    #pragma unroll
    for (int kk = 0; kk < 2; ++kk) {
      int k0 = (wave*2 + kk)*32 + quad*8;
      bf16x8 bfrag = *reinterpret_cast<const bf16x8*>(&s_aT[mrow][k0]);
      #pragma unroll
      for (int mt = 0; mt < 6; ++mt) {
        bf16x8 afrag = *reinterpret_cast<const bf16x8*>(&s_pfT[mt*16 + mrow][k0]);
        accC[mt] = __builtin_amdgcn_mfma_f32_16x16x32_bf16(afrag, bfrag, accC[mt], 0, 0, 0);
      }
    }
    __syncthreads();
  }
  if (mrow < 4) {     // C/D: col=lane&15 (=s), row=quad*4+reg (=c within tile)
    #pragma unroll
    for (int mt = 0; mt < 6; ++mt)
      #pragma unroll
      for (int r = 0; r < 4; ++r) {
        int c = mt*16 + quad*4 + r;
        atomicAdd(&ws[OFF_NUM1 + (tile*96 + c)*4 + mrow], accC[mt][r]);
      }
  }
  for (int m2 = 1; m2 < 64; m2 <<= 1) {
    dden[0] += __shfl_xor(dden[0], m2, 64); dden[1] += __shfl_xor(dden[1], m2, 64);
    dden[2] += __shfl_xor(dden[2], m2, 64); dden[3] += __shfl_xor(dden[3], m2, 64);
  }
  if (lane == 0) {
    atomicAdd(&ws[OFF_DEN1 + tile*4 + 0], dden[0]);
    atomicAdd(&ws[OFF_DEN1 + tile*4 + 1], dden[1]);
    atomicAdd(&ws[OFF_DEN1 + tile*4 + 2], dden[2]);
    atomicAdd(&ws[OFF_DEN1 + tile*4 + 3], dden[3]);
  }
}

// K5: SSN iter1. fin1 fused into preamble (cen_pf1/norm1 recomputed per WG).
// Same wide-load structure for feat; g read back as coalesced float4.
__global__ __launch_bounds__(256) void k_pass3(const float* __restrict__ feat,
    const int* __restrict__ gt, float* __restrict__ ws, float* __restrict__ out) {
  int wg = blockIdx.x, tile = wg >> 2, seg = wg & 3, tid = threadIdx.x;
  int b = tile >> 6, tl = tile & 63, f1 = tl >> 3, f2 = tl & 7;
  __shared__ float s_cpf1[384];
  __shared__ float s_n1[4];
  __shared__ __align__(16) unsigned short s_pfT[96][264];
  __shared__ __align__(16) unsigned short s_aT[16][264];
  __shared__ __align__(16) float s_part[2][4][260];
  __shared__ float s_hist[64];
  if (tid < 4) s_n1[tid] = 0.f;
  if (tid < 64) s_hist[tid] = 0.f;
  for (int i = tid; i < 16*264; i += 256) (&s_aT[0][0])[i] = 0;
  __syncthreads();
  // fused fin1: cen_pf1 = NUM1/(DEN1+eps), norm1 = |cen_pf1|^2 per s
  for (int i = tid; i < 384; i += 256) {
    float den = ws[OFF_DEN1 + tile*4 + (i & 3)];
    float v = ws[OFF_NUM1 + tile*384 + i] / (den + 1e-16f);
    s_cpf1[i] = v;
    atomicAdd(&s_n1[i & 3], v*v);
  }
  __syncthreads();
  int lane = tid & 63, wave = tid >> 6;
  int mrow = lane & 15, quad = lane >> 4;
  int q4 = lane * 4;
  f32x4 zero4 = {0.f, 0.f, 0.f, 0.f};
  f32x4 accC[6] = {zero4, zero4, zero4, zero4, zero4, zero4};
  float oden[4] = {0.f, 0.f, 0.f, 0.f};
  for (int chunk = 0; chunk < 4; ++chunk) {
    int pq = seg*1024 + chunk*256 + q4;
    int goq = (f1*64 + (pq >> 6))*512 + f2*64 + (pq & 63);
    const float* fq = feat + (size_t)(b*96)*262144 + goq;
    f32x4 dpp[4] = {zero4, zero4, zero4, zero4};
    f32x4 vv[8];
    #pragma unroll
    for (int r = 0; r < 3; ++r) {
      #pragma unroll
      for (int i = 0; i < 8; ++i)
        vv[i] = *reinterpret_cast<const f32x4*>(fq + (size_t)(wave + 4*(r*8 + i))*262144);
      #pragma unroll
      for (int i = 0; i < 8; ++i) {
        int ch = wave + 4*(r*8 + i);
        u16x4 uu = { f2bf(vv[i][0]), f2bf(vv[i][1]), f2bf(vv[i][2]), f2bf(vv[i][3]) };
        *reinterpret_cast<u16x4*>(&s_pfT[ch][q4]) = uu;
        #pragma unroll
        for (int s = 0; s < 4; ++s) dpp[s] += vv[i] * s_cpf1[ch*4 + s];
      }
    }
    if (wave >= 2) {
      #pragma unroll
      for (int s = 0; s < 4; ++s)
        *reinterpret_cast<f32x4*>(&s_part[wave-2][s][q4]) = dpp[s];
    }
    __syncthreads();
    if (wave < 2) {
      #pragma unroll
      for (int s = 0; s < 4; ++s) {
        f32x4 t = *reinterpret_cast<f32x4*>(&s_part[wave][s][q4]);
        t += dpp[s];
        *reinterpret_cast<f32x4*>(&s_part[wave][s][q4]) = t;
      }
    }
    __syncthreads();
    // score phase: px = tid
    int p = seg*1024 + chunk*256 + tid;
    int y = p >> 6, xx = p & 63;
    int go = (f1*64 + y)*512 + f2*64 + xx;
    f32x4 gv = *reinterpret_cast<const f32x4*>(ws + OFF_G + ((size_t)tile << 14) + (size_t)p*4);
    float p0 = s_part[0][0][tid] + s_part[1][0][tid];
    float p1 = s_part[0][1][tid] + s_part[1][1][tid];
    float p2 = s_part[0][2][tid] + s_part[1][2][tid];
    float p3 = s_part[0][3][tid] + s_part[1][3][tid];
    float sc0 = gv[0] + 2.f*p0 - s_n1[0];
    float sc1 = gv[1] + 2.f*p1 - s_n1[1];
    float sc2 = gv[2] + 2.f*p2 - s_n1[2];
    float sc3 = gv[3] + 2.f*p3 - s_n1[3];
    int ss = 0; float best = sc0;
    if (sc1 > best) { best = sc1; ss = 1; }
    if (sc2 > best) { best = sc2; ss = 2; }
    if (sc3 > best) { best = sc3; ss = 3; }
    float se = expf(sc0-best) + expf(sc1-best) + expf(sc2-best) + expf(sc3-best);
    float sim = 1.f / se;
    unsigned short sb = f2bf(sim);
    s_aT[0][tid] = (ss == 0) ? sb : (unsigned short)0;
    s_aT[1][tid] = (ss == 1) ? sb : (unsigned short)0;
    s_aT[2][tid] = (ss == 2) ? sb : (unsigned short)0;
    s_aT[3][tid] = (ss == 3) ? sb : (unsigned short)0;
    oden[ss] += sim;
    int gvv = gt[b*262144 + go];
    atomicAdd(&s_hist[ss*16 + gvv], 1.f);
    out[OUT_SP + b*262144 + go] = (float)(tl*4 + ss);
    __syncthreads();
    #pragma unroll
    for (int kk = 0; kk < 2; ++kk) {
      int k0 = (wave*2 + kk)*32 + quad*8;
      bf16x8 bfrag = *reinterpret_cast<const bf16x8*>(&s_aT[mrow][k0]);
      #pragma unroll
      for (int mt = 0; mt < 6; ++mt) {
        bf16x8 afrag = *reinterpret_cast<const bf16x8*>(&s_pfT[mt*16 + mrow][k0]);
        accC[mt] = __builtin_amdgcn_mfma_f32_16x16x32_bf16(afrag, bfrag, accC[mt], 0, 0, 0);
      }
    }
    __syncthreads();
  }
  if (mrow < 4) {
    #pragma unroll
    for (int mt = 0; mt < 6; ++mt)
      #pragma unroll
      for (int r = 0; r < 4; ++r) {
        int c = mt*16 + quad*4 + r;
        atomicAdd(&ws[OFF_OUTNUM + (tile*96 + c)*4 + mrow], accC[mt][r]);
      }
  }
  for (int m2 = 1; m2 < 64; m2 <<= 1) {
    oden[0] += __shfl_xor(oden[0], m2, 64); oden[1] += __shfl_xor(oden[1], m2, 64);
    oden[2] += __shfl_xor(oden[2], m2, 64); oden[3] += __shfl_xor(oden[3], m2, 64);
  }
  if (lane == 0) {
    atomicAdd(&ws[OFF_OUTDEN + tile*4 + 0], oden[0]);
    atomicAdd(&ws[OFF_OUTDEN + tile*4 + 1], oden[1]);
    atomicAdd(&ws[OFF_OUTDEN + tile*4 + 2], oden[2]);
    atomicAdd(&ws[OFF_OUTDEN + tile*4 + 3], oden[3]);
  }
  if (tid < 64) atomicAdd(&ws[OFF_LABELS + tile*64 + tid], s_hist[tid]);
}

// K6: epilogue -> center_feat and labels
__global__ __launch_bounds__(384) void k_out(const float* __restrict__ ws,
                                             float* __restrict__ out) {
  int tile = blockIdx.x, tid = threadIdx.x;
  int b = tile >> 6, tl = tile & 63;
  int c = tid % 96, s = tid / 96;
  float od = ws[OFF_OUTDEN + tile*4 + s];
  float v = (ws[OFF_OUTNUM + (tile*96 + c)*4 + s] + ws[OFF_CENPF0 + (tile*96 + c)*4 + s]) / (od + 1.f);
  out[OUT_CF + (size_t)(b*256 + tl*4 + s)*96 + c] = v;
  if (tid < 64) {
    int s2 = tid >> 4, cls = tid & 15;
    float cnt = ws[OFF_LABELS + tile*64 + tid];
    out[OUT_LB + (b*16 + cls)*256 + tl*4 + s2] = cnt;
  }
}

extern "C" void kernel_launch(void* const* d_in, const int* in_sizes, int n_in,
                              void* d_out, int out_size, void* d_ws, size_t ws_size,
                              hipStream_t stream) {
  const float* x    = (const float*)d_in[0];
  const float* feat = (const float*)d_in[1];
  const float* sdf  = (const float*)d_in[2];
  const float* Wf   = (const float*)d_in[3];
  const float* bfv  = (const float*)d_in[4];
  const float* Wsdf = (const float*)d_in[5];
  const float* bsdf = (const float*)d_in[6];
  const int* gt = (const int*)d_in[7];
  float* ws = (float*)d_ws;
  float* out = (float*)d_out;

  k_pool   <<<dim3(318, 8), 256, 0, stream>>>(x, feat, sdf, ws);
  k_centers<<<128, 384, 0, stream>>>(Wf, bfv, Wsdf, bsdf, ws);
  k_pass2  <<<512, 256, 0, stream>>>(x, feat, sdf, ws);
  k_pass3  <<<512, 256, 0, stream>>>(feat, gt, ws, out);
  k_out    <<<128, 384, 0, stream>>>(ws, out);
}